// Round 15
// baseline (258.408 us; speedup 1.0000x reference)
//
#include <hip/hip_runtime.h>
#include <hip/hip_bf16.h>
#include <hip/hip_fp16.h>
#include <stdint.h>

// Problem constants (B=2, T=2048, D=1024, H=16, hd=64)
#define B_    2
#define T_    2048
#define DM    1024
#define NH    16
#define HD    64
#define M_    (B_ * T_)      // 4096 rows of X
#define N_QKV (3 * DM)       // 3072

typedef __attribute__((ext_vector_type(8))) __bf16 bf16x8;
typedef __attribute__((ext_vector_type(4))) float  v4f;
typedef __attribute__((ext_vector_type(2))) __fp16 fp16x2;   // cvt_pkrtz return type
typedef __attribute__((ext_vector_type(4))) _Float16 h4;
typedef __attribute__((ext_vector_type(8))) _Float16 h8;
typedef __hip_bfloat16 bf16;

// Q is PRE-SCALED by log2(e)/64 in the QKV epilogue: P = exp2(S') directly.
#define EXP_SC 0.022542110013890053f

// ---- async global->LDS, 16B per lane (LDS dest must be lane-contiguous) ----
__device__ __forceinline__ void gld_lds16(const void* g, void* l) {
  __builtin_amdgcn_global_load_lds(
      (const __attribute__((address_space(1))) void*)(g),
      (__attribute__((address_space(3))) void*)(l), 16, 0, 0);
}

// XOR-swizzle: granule g' in LDS holds global granule g = g' ^ (row & mask).

// ---------------- fused prep: cast X + transpose both weights ----------------
__global__ __launch_bounds__(256) void prep(
    const float* __restrict__ x, const float* __restrict__ Wqkv,
    const float* __restrict__ Wproj, bf16* __restrict__ Xb,
    bf16* __restrict__ WqkvT, bf16* __restrict__ WprojT) {
  const int f = blockIdx.x;
  if (f < 4096) {               // cast X -> bf16
    int i = (f * 256 + threadIdx.x) * 4;
    float4 v = *(const float4*)(x + i);
    union { bf16 h[4]; ushort4 u; } r;
    r.h[0] = __float2bfloat16(v.x); r.h[1] = __float2bfloat16(v.y);
    r.h[2] = __float2bfloat16(v.z); r.h[3] = __float2bfloat16(v.w);
    *(ushort4*)(Xb + i) = r.u;
    return;
  }
  __shared__ float tile[32][33];
  const float* in; bf16* out; int C, bx, by;
  if (f < 4096 + 3072) { int g = f - 4096; bx = g % 96; by = g / 96;
                         in = Wqkv;  out = WqkvT;  C = N_QKV; }
  else                 { int g = f - 7168; bx = g % 32; by = g / 32;
                         in = Wproj; out = WprojT; C = DM; }
  const int R = DM;
  int tx = threadIdx.x & 31, ty = threadIdx.x >> 5;
  int c0 = bx * 32, r0 = by * 32;
  #pragma unroll
  for (int i = ty; i < 32; i += 8)
    tile[i][tx] = in[(size_t)(r0 + i) * C + c0 + tx];
  __syncthreads();
  #pragma unroll
  for (int i = ty; i < 32; i += 8)
    out[(size_t)(c0 + i) * R + r0 + tx] = __float2bfloat16(tile[tx][i]);
}

// ---------------- 128x128 BT-GEMM (A[M][K] bf16, BT[N][K] bf16) ----------------
// XOR-swizzled LDS. MODE 0: C fp32 plain store. MODE 1: QKV split --
// Q bf16 (PRE-SCALED by EXP_SC) and K bf16, [bh][t][d] scalar stores;
// V-blocks (n0 >= 2048) transpose their 128x128 tile through LDS (packed h4
// writes exploiting the C-layout's 4 consecutive rows) and store V^T
// [bh][d][t] f16 with coalesced b128 -- no separate transpose kernel.
template <int MODE>
__global__ __launch_bounds__(256) void gemm_bt(
    const bf16* __restrict__ A, const bf16* __restrict__ BT,
    float* __restrict__ Cf, bf16* __restrict__ qb, bf16* __restrict__ kb,
    _Float16* __restrict__ vtb, int M, int N, int K) {
  __shared__ char smem[35840];
  bf16* As = (bf16*)smem;            // [m][g-swizzled k] 16KB
  bf16* Bs = (bf16*)(smem + 16384);  // [n][g-swizzled k] 16KB
  const int tid = threadIdx.x;
  const int l = tid & 63, w = tid >> 6;
  const int wm = w >> 1, wn = w & 1;          // 2x2 wave grid, 64x64 C each
  const int m0 = blockIdx.y * 128, n0 = blockIdx.x * 128;
  const int fr = l & 15;                      // fragment row (m or n)
  const int lg = l >> 4;                      // lane granule group 0..3
  const int g4 = lg * 4;

  v4f acc[4][4] = {};

  for (int kt = 0; kt < K; kt += 64) {
    __syncthreads();
    #pragma unroll
    for (int i = 0; i < 4; ++i) {
      int p = i * 256 + tid;                  // granule index 0..1023
      int row = p >> 3, g = (p & 7) ^ (row & 7);
      gld_lds16(A + (size_t)(m0 + row) * K + kt + g * 8, As + p * 8);
      gld_lds16(BT + (size_t)(n0 + row) * K + kt + g * 8, Bs + p * 8);
    }
    __syncthreads();
    #pragma unroll
    for (int kk = 0; kk < 64; kk += 32) {
      const int gl = (kk >> 3) + lg;          // logical granule 0..7
      bf16x8 af[4], bfr[4];
      #pragma unroll
      for (int i = 0; i < 4; ++i) {
        int row = wm * 64 + i * 16 + fr;
        af[i] = *(const bf16x8*)(As + row * 64 + (gl ^ (fr & 7)) * 8);
      }
      #pragma unroll
      for (int i = 0; i < 4; ++i) {
        int row = wn * 64 + i * 16 + fr;
        bfr[i] = *(const bf16x8*)(Bs + row * 64 + (gl ^ (fr & 7)) * 8);
      }
      #pragma unroll
      for (int mi = 0; mi < 4; ++mi)
        #pragma unroll
        for (int ni = 0; ni < 4; ++ni)
          acc[mi][ni] = __builtin_amdgcn_mfma_f32_16x16x32_bf16(
              af[mi], bfr[ni], acc[mi][ni], 0, 0, 0);
    }
  }

  // V-block epilogue (MODE 1, n0 >= 2048): LDS transpose, b128 V^T stores.
  if constexpr (MODE == 1) {
    if (n0 >= 2048) {
      const int b = m0 >> 11;
      const int vt0 = m0 & 2047;                     // time index base (BUGFIX)
      const int hbase = ((n0 - 2048) >> 6) & 15;     // head of col group 0
      _Float16 (*Vt)[136] = (_Float16(*)[136])smem;  // [d=64][t=128+8] 17.4KB
      #pragma unroll
      for (int half = 0; half < 2; ++half) {
        __syncthreads();     // As/Bs reads done / previous half stored
        if (wn == half) {
          #pragma unroll
          for (int mi = 0; mi < 4; ++mi) {
            int trow = wm * 64 + mi * 16 + g4;
            #pragma unroll
            for (int ni = 0; ni < 4; ++ni) {
              h4 pv;
              #pragma unroll
              for (int r = 0; r < 4; ++r) pv[r] = (_Float16)acc[mi][ni][r];
              *(h4*)(&Vt[ni * 16 + fr][trow]) = pv;
            }
          }
        }
        __syncthreads();
        size_t bh = (size_t)(b * NH + ((hbase + half) & 15));
        #pragma unroll
        for (int i = 0; i < 4; ++i) {
          int p = i * 256 + tid;               // 1024 granules (64 d x 16)
          int d = p >> 4, tg = (p & 15) * 8;
          *(uint4*)(vtb + (bh * HD + d) * T_ + vt0 + tg) = *(uint4*)(&Vt[d][tg]);
        }
      }
      return;
    }
  }

  // Scalar epilogue. C/D layout: col = lane&15, row = (lane>>4)*4 + reg.
  #pragma unroll
  for (int mi = 0; mi < 4; ++mi) {
    #pragma unroll
    for (int ni = 0; ni < 4; ++ni) {
      #pragma unroll
      for (int r = 0; r < 4; ++r) {
        int gm = m0 + wm * 64 + mi * 16 + g4 + r;
        int gn = n0 + wn * 64 + ni * 16 + fr;
        float v = acc[mi][ni][r];
        if constexpr (MODE == 0) {
          Cf[(size_t)gm * N + gn] = v;
        } else {
          int b = gm >> 11, t = gm & 2047;            // T=2048
          int s = gn >> 10, h = (gn >> 6) & 15, d = gn & 63;
          size_t bh = (size_t)(b * NH + h);
          if (s == 0) qb[(bh * T_ + t) * HD + d] = __float2bfloat16(v * EXP_SC);
          else        kb[(bh * T_ + t) * HD + d] = __float2bfloat16(v);
        }
      }
    }
  }
}

// ---------------- 128x64 BT-GEMM for the projection ----------------
__global__ __launch_bounds__(256) void gemm_bt_n64(
    const bf16* __restrict__ A, const bf16* __restrict__ BT,
    float* __restrict__ Cf, int M, int N, int K) {
  __shared__ bf16 As[128 * 64];   // 16KB
  __shared__ bf16 Bs[64 * 64];    //  8KB
  const int tid = threadIdx.x;
  const int l = tid & 63, w = tid >> 6;
  const int wm = w >> 1, wn = w & 1;          // 64m x 32n per wave
  const int m0 = blockIdx.y * 128, n0 = blockIdx.x * 64;
  const int fr = l & 15;
  const int lg = l >> 4;

  v4f acc[4][2] = {};

  for (int kt = 0; kt < K; kt += 64) {
    __syncthreads();
    #pragma unroll
    for (int i = 0; i < 4; ++i) {
      int p = i * 256 + tid;
      int row = p >> 3, g = (p & 7) ^ (row & 7);
      gld_lds16(A + (size_t)(m0 + row) * K + kt + g * 8, As + p * 8);
    }
    #pragma unroll
    for (int i = 0; i < 2; ++i) {
      int p = i * 256 + tid;
      int row = p >> 3, g = (p & 7) ^ (row & 7);
      gld_lds16(BT + (size_t)(n0 + row) * K + kt + g * 8, Bs + p * 8);
    }
    __syncthreads();
    #pragma unroll
    for (int kk = 0; kk < 64; kk += 32) {
      const int gl = (kk >> 3) + lg;
      bf16x8 af[4], bfr[2];
      #pragma unroll
      for (int i = 0; i < 4; ++i) {
        int row = wm * 64 + i * 16 + fr;
        af[i] = *(const bf16x8*)(As + row * 64 + (gl ^ (fr & 7)) * 8);
      }
      #pragma unroll
      for (int i = 0; i < 2; ++i) {
        int row = wn * 32 + i * 16 + fr;
        bfr[i] = *(const bf16x8*)(Bs + row * 64 + (gl ^ (fr & 7)) * 8);
      }
      #pragma unroll
      for (int mi = 0; mi < 4; ++mi)
        #pragma unroll
        for (int ni = 0; ni < 2; ++ni)
          acc[mi][ni] = __builtin_amdgcn_mfma_f32_16x16x32_bf16(
              af[mi], bfr[ni], acc[mi][ni], 0, 0, 0);
    }
  }

  #pragma unroll
  for (int mi = 0; mi < 4; ++mi)
    #pragma unroll
    for (int ni = 0; ni < 2; ++ni)
      #pragma unroll
      for (int r = 0; r < 4; ++r) {
        int gm = m0 + wm * 64 + mi * 16 + (l >> 4) * 4 + r;
        int gn = n0 + wn * 32 + ni * 16 + (l & 15);
        Cf[(size_t)gm * N + gn] = acc[mi][ni][r];
      }
}

// ---------------- fused attention: block key-split (z=2) + atomic combine ------
// Proven q128/Kt128 tile (round 12); gridDim.z=2 splits the 2048 keys into two
// 1024-key halves -> 1024 blocks = 4/CU, 16 waves/CU, per-q staging UNCHANGED
// (the round-13 failure mode). Partials are purely additive (no max
// subtraction) -> in-block key-half LDS combine as before, then exactly 2
// commutative f32 atomic adds per output element (deterministic) into Oacc /
// Lacc; a separate normalize kernel divides and casts to bf16.
__global__ __launch_bounds__(256) void flash_attn(
    const bf16* __restrict__ Qg, const bf16* __restrict__ Kg,
    const _Float16* __restrict__ VTg, float* __restrict__ Oacc,
    float* __restrict__ Lacc) {
  __shared__ char smem[53248];
  bf16*     Ks = (bf16*)smem;                         // [128][64] swizzled, 16KB
  _Float16* Vs = (_Float16*)(smem + 16384);           // [64][128] swizzled, 16KB
  _Float16 (*Ps)[40] = (_Float16(*)[40])(smem + 32768); // [4*64][40], 20KB
  float*    Obuf = (float*)smem;                      // combine alias: [2][64][68]
  float*    Lbuf = (float*)(smem + 34816);            // combine alias: [2][64]

  const int tid = threadIdx.x, l = tid & 63, w = tid >> 6;
  const int qh = w & 1, kh = w >> 1;
  const int fr = l & 15, fk = (l >> 4) * 8, g4 = (l >> 4) * 4, lg = l >> 4;
  const int bh = blockIdx.y, qt = blockIdx.x;
  const int kz0 = (int)blockIdx.z * 1024;      // this block's key range start
  const int q0 = qt * 128 + qh * 64;           // wave's first q-row
  const size_t base  = (size_t)bh * T_ * HD;   // Q/K base
  const size_t baseV = (size_t)bh * HD * T_;   // V^T base
  _Float16 (*Pw)[40] = Ps + w * 64;            // wave-private P rows

  // Q fragments (B-operand of S^T: n=q, k=d) in registers, loaded once.
  bf16x8 qB[4][2];
  #pragma unroll
  for (int qf = 0; qf < 4; ++qf)
    #pragma unroll
    for (int kki = 0; kki < 2; ++kki)
      qB[qf][kki] = *(const bf16x8*)(
          Qg + base + (size_t)(q0 + qf * 16 + fr) * HD + kki * 32 + fk);

  h8 ones;
  #pragma unroll
  for (int j = 0; j < 8; ++j) ones[j] = (_Float16)1.0f;

  v4f o[4][4] = {};     // partial O: m=q (4 frags), n=d (4 frags)
  v4f lacc[4] = {};     // partial row sums

  for (int kt = kz0; kt < kz0 + 1024; kt += 128) {
    __syncthreads();
    #pragma unroll
    for (int i = 0; i < 4; ++i) {
      int p = i * 256 + tid;                   // 1024 granules each
      int krow = p >> 3, kg = (p & 7) ^ (krow & 7);
      gld_lds16(Kg + base + (size_t)(kt + krow) * HD + kg * 8, Ks + p * 8);
      int vrow = p >> 4, vg = (p & 15) ^ (vrow & 15);
      gld_lds16(VTg + baseV + (size_t)vrow * T_ + kt + vg * 8, Vs + p * 8);
    }
    __syncthreads();

    // Wave's 64 keys (half kh) in 2 chunks of 32: S^T -> exp2 -> store -> PV.
    #pragma unroll
    for (int c = 0; c < 2; ++c) {
      const int kkg = kh * 2 + c;              // 32-key chunk 0..3 within tile
      #pragma unroll
      for (int hf = 0; hf < 2; ++hf) {
        const int kf = kkg * 2 + hf;           // 16-key frag 0..7
        v4f st[4] = {};
        #pragma unroll
        for (int kki = 0; kki < 2; ++kki) {
          int row = kf * 16 + fr;
          bf16x8 ak = *(const bf16x8*)(
              Ks + row * 64 + ((kki * 4 + lg) ^ (fr & 7)) * 8);
          #pragma unroll
          for (int qf = 0; qf < 4; ++qf)
            st[qf] = __builtin_amdgcn_mfma_f32_16x16x32_bf16(
                ak, qB[qf][kki], st[qf], 0, 0, 0);
        }
        #pragma unroll
        for (int qf = 0; qf < 4; ++qf) {
          union { fp16x2 p2[2]; h4 p4; } u;
          u.p2[0] = __builtin_amdgcn_cvt_pkrtz(
              __builtin_amdgcn_exp2f(st[qf][0]),
              __builtin_amdgcn_exp2f(st[qf][1]));
          u.p2[1] = __builtin_amdgcn_cvt_pkrtz(
              __builtin_amdgcn_exp2f(st[qf][2]),
              __builtin_amdgcn_exp2f(st[qf][3]));
          *(h4*)(&Pw[qf * 16 + fr][hf * 16 + g4]) = u.p4;
        }
      }
      h8 ap[4], bv[4];
      #pragma unroll
      for (int qf = 0; qf < 4; ++qf)
        ap[qf] = *(const h8*)(&Pw[qf * 16 + fr][fk]);
      #pragma unroll
      for (int nf = 0; nf < 4; ++nf) {
        int row = nf * 16 + fr;
        bv[nf] = *(const h8*)(Vs + row * 128 + ((kkg * 4 + lg) ^ fr) * 8);
      }
      #pragma unroll
      for (int qf = 0; qf < 4; ++qf) {
        lacc[qf] = __builtin_amdgcn_mfma_f32_16x16x32_f16(
            ap[qf], ones, lacc[qf], 0, 0, 0);
        #pragma unroll
        for (int nf = 0; nf < 4; ++nf)
          o[qf][nf] = __builtin_amdgcn_mfma_f32_16x16x32_f16(
              ap[qf], bv[nf], o[qf][nf], 0, 0, 0);
      }
    }
  }

  // Combine key halves in-block, then 2-way atomic combine across z-blocks.
  __syncthreads();           // all tiles done; Ks/Vs/Ps now dead
  if (w >= 2) {
    #pragma unroll
    for (int qf = 0; qf < 4; ++qf)
      #pragma unroll
      for (int r = 0; r < 4; ++r) {
        int row = qf * 16 + g4 + r;
        #pragma unroll
        for (int nf = 0; nf < 4; ++nf)
          Obuf[(qh * 64 + row) * 68 + nf * 16 + fr] = o[qf][nf][r];
        if (fr == 0) Lbuf[qh * 64 + row] = lacc[qf][r];
      }
  }
  __syncthreads();
  if (w < 2) {
    int b = bh >> 4, h = bh & 15;
    #pragma unroll
    for (int qf = 0; qf < 4; ++qf) {
      #pragma unroll
      for (int r = 0; r < 4; ++r) {
        int row = qf * 16 + g4 + r;
        int t = q0 + row;
        float lsum = lacc[qf][r] + Lbuf[qh * 64 + row];
        if (fr == 0)
          unsafeAtomicAdd(&Lacc[(((size_t)(b * T_ + t)) << 4) + h], lsum);
        #pragma unroll
        for (int nf = 0; nf < 4; ++nf) {
          float val = o[qf][nf][r] + Obuf[(qh * 64 + row) * 68 + nf * 16 + fr];
          unsafeAtomicAdd(
              &Oacc[(size_t)(b * T_ + t) * DM + h * HD + nf * 16 + fr], val);
        }
      }
    }
  }
}

// ---------------- normalize: Ab = bf16(Oacc / Lacc) ----------------
__global__ __launch_bounds__(256) void normalize(
    const float* __restrict__ Oacc, const float* __restrict__ Lacc,
    bf16* __restrict__ Ab) {
  int i = (blockIdx.x * 256 + threadIdx.x) * 4;
  float4 v = *(const float4*)(Oacc + i);
  float inv = 1.0f / Lacc[((size_t)(i >> 10) << 4) + ((i & 1023) >> 6)];
  union { bf16 h[4]; ushort4 u; } r;
  r.h[0] = __float2bfloat16(v.x * inv); r.h[1] = __float2bfloat16(v.y * inv);
  r.h[2] = __float2bfloat16(v.z * inv); r.h[3] = __float2bfloat16(v.w * inv);
  *(ushort4*)(Ab + i) = r.u;
}

extern "C" void kernel_launch(void* const* d_in, const int* in_sizes, int n_in,
                              void* d_out, int out_size, void* d_ws, size_t ws_size,
                              hipStream_t stream) {
  const float* x     = (const float*)d_in[0];
  const float* Wqkv  = (const float*)d_in[1];
  const float* Wproj = (const float*)d_in[2];
  float* out = (float*)d_out;
  char* ws = (char*)d_ws;

  // Workspace layout (48 MB), time-multiplexed:
  //  0-16 : Xb (0-8) + WqkvT (8-14) during prep/gemm1; then Oacc f32 (16 MB)
  // 16-24 : Qb bf16 (pre-scaled); then Ab bf16 (normalize output)
  // 24-32 : Kb bf16
  // 32-40 : VTh f16 (written directly by gemm1's V-block LDS-transpose)
  // 40-42 : WprojT (prep -> proj; untouched in between)
  // 42-42.25 : Lacc f32 (B*T*NH = 64K floats)
  bf16*     Xb     = (bf16*)(ws);
  bf16*     WqkvT  = (bf16*)(ws + (size_t)( 8u << 20));
  float*    Oacc   = (float*)(ws);
  bf16*     Qb     = (bf16*)(ws + (size_t)(16u << 20));
  bf16*     Ab     = (bf16*)(ws + (size_t)(16u << 20));
  bf16*     Kb     = (bf16*)(ws + (size_t)(24u << 20));
  _Float16* VTh    = (_Float16*)(ws + (size_t)(32u << 20));
  bf16*     WprojT = (bf16*)(ws + (size_t)(40u << 20));
  float*    Lacc   = (float*)(ws + (size_t)(42u << 20));

  prep<<<8192, 256, 0, stream>>>(x, Wqkv, Wproj, Xb, WqkvT, WprojT);

  gemm_bt<1><<<dim3(N_QKV / 128, M_ / 128), 256, 0, stream>>>(
      Xb, WqkvT, nullptr, Qb, Kb, VTh, M_, N_QKV, DM);

  // Zero the f32 accumulators (Xb/WqkvT are dead now).
  (void)hipMemsetAsync(Oacc, 0, (size_t)M_ * DM * sizeof(float), stream);
  (void)hipMemsetAsync(Lacc, 0, (size_t)M_ * NH * sizeof(float), stream);

  flash_attn<<<dim3(T_ / 128, B_ * NH, 2), 256, 0, stream>>>(
      Qb, Kb, VTh, Oacc, Lacc);

  normalize<<<(M_ * DM) / 1024, 256, 0, stream>>>(Oacc, Lacc, Ab);

  gemm_bt_n64<<<dim3(DM / 64, M_ / 128), 256, 0, stream>>>(
      Ab, WprojT, out, M_, DM, DM);
}

// Round 16
// 192.207 us; speedup vs baseline: 1.3444x; 1.3444x over previous
//
#include <hip/hip_runtime.h>
#include <hip/hip_bf16.h>
#include <hip/hip_fp16.h>
#include <stdint.h>

// Problem constants (B=2, T=2048, D=1024, H=16, hd=64)
#define B_    2
#define T_    2048
#define DM    1024
#define NH    16
#define HD    64
#define M_    (B_ * T_)      // 4096 rows of X
#define N_QKV (3 * DM)       // 3072

typedef __attribute__((ext_vector_type(8))) __bf16 bf16x8;
typedef __attribute__((ext_vector_type(4))) float  v4f;
typedef __attribute__((ext_vector_type(2))) __fp16 fp16x2;   // cvt_pkrtz return type
typedef __attribute__((ext_vector_type(4))) _Float16 h4;
typedef __attribute__((ext_vector_type(8))) _Float16 h8;
typedef __hip_bfloat16 bf16;

// Q is PRE-SCALED by log2(e)/64 in the QKV epilogue: P = exp2(S') directly.
#define EXP_SC 0.022542110013890053f

// ---- async global->LDS, 16B per lane (LDS dest must be lane-contiguous) ----
__device__ __forceinline__ void gld_lds16(const void* g, void* l) {
  __builtin_amdgcn_global_load_lds(
      (const __attribute__((address_space(1))) void*)(g),
      (__attribute__((address_space(3))) void*)(l), 16, 0, 0);
}

// XOR-swizzle: granule g' in LDS holds global granule g = g' ^ (row & mask).

// ---------------- fused prep: cast X + transpose both weights ----------------
__global__ __launch_bounds__(256) void prep(
    const float* __restrict__ x, const float* __restrict__ Wqkv,
    const float* __restrict__ Wproj, bf16* __restrict__ Xb,
    bf16* __restrict__ WqkvT, bf16* __restrict__ WprojT) {
  const int f = blockIdx.x;
  if (f < 4096) {               // cast X -> bf16
    int i = (f * 256 + threadIdx.x) * 4;
    float4 v = *(const float4*)(x + i);
    union { bf16 h[4]; ushort4 u; } r;
    r.h[0] = __float2bfloat16(v.x); r.h[1] = __float2bfloat16(v.y);
    r.h[2] = __float2bfloat16(v.z); r.h[3] = __float2bfloat16(v.w);
    *(ushort4*)(Xb + i) = r.u;
    return;
  }
  __shared__ float tile[32][33];
  const float* in; bf16* out; int C, bx, by;
  if (f < 4096 + 3072) { int g = f - 4096; bx = g % 96; by = g / 96;
                         in = Wqkv;  out = WqkvT;  C = N_QKV; }
  else                 { int g = f - 7168; bx = g % 32; by = g / 32;
                         in = Wproj; out = WprojT; C = DM; }
  const int R = DM;
  int tx = threadIdx.x & 31, ty = threadIdx.x >> 5;
  int c0 = bx * 32, r0 = by * 32;
  #pragma unroll
  for (int i = ty; i < 32; i += 8)
    tile[i][tx] = in[(size_t)(r0 + i) * C + c0 + tx];
  __syncthreads();
  #pragma unroll
  for (int i = ty; i < 32; i += 8)
    out[(size_t)(c0 + i) * R + r0 + tx] = __float2bfloat16(tile[tx][i]);
}

// ---------------- 128x128 BT-GEMM (A[M][K] bf16, BT[N][K] bf16) ----------------
// XOR-swizzled LDS. MODE 0: C fp32 plain store. MODE 1: QKV split --
// Q bf16 (PRE-SCALED by EXP_SC) and K bf16, [bh][t][d] scalar stores;
// V-blocks (n0 >= 2048) transpose their 128x128 tile through LDS (packed h4
// writes exploiting the C-layout's 4 consecutive rows) and store V^T
// [bh][d][t] f16 with coalesced b128 -- no separate transpose kernel.
template <int MODE>
__global__ __launch_bounds__(256) void gemm_bt(
    const bf16* __restrict__ A, const bf16* __restrict__ BT,
    float* __restrict__ Cf, bf16* __restrict__ qb, bf16* __restrict__ kb,
    _Float16* __restrict__ vtb, int M, int N, int K) {
  __shared__ char smem[35840];
  bf16* As = (bf16*)smem;            // [m][g-swizzled k] 16KB
  bf16* Bs = (bf16*)(smem + 16384);  // [n][g-swizzled k] 16KB
  const int tid = threadIdx.x;
  const int l = tid & 63, w = tid >> 6;
  const int wm = w >> 1, wn = w & 1;          // 2x2 wave grid, 64x64 C each
  const int m0 = blockIdx.y * 128, n0 = blockIdx.x * 128;
  const int fr = l & 15;                      // fragment row (m or n)
  const int lg = l >> 4;                      // lane granule group 0..3
  const int g4 = lg * 4;

  v4f acc[4][4] = {};

  for (int kt = 0; kt < K; kt += 64) {
    __syncthreads();
    #pragma unroll
    for (int i = 0; i < 4; ++i) {
      int p = i * 256 + tid;                  // granule index 0..1023
      int row = p >> 3, g = (p & 7) ^ (row & 7);
      gld_lds16(A + (size_t)(m0 + row) * K + kt + g * 8, As + p * 8);
      gld_lds16(BT + (size_t)(n0 + row) * K + kt + g * 8, Bs + p * 8);
    }
    __syncthreads();
    #pragma unroll
    for (int kk = 0; kk < 64; kk += 32) {
      const int gl = (kk >> 3) + lg;          // logical granule 0..7
      bf16x8 af[4], bfr[4];
      #pragma unroll
      for (int i = 0; i < 4; ++i) {
        int row = wm * 64 + i * 16 + fr;
        af[i] = *(const bf16x8*)(As + row * 64 + (gl ^ (fr & 7)) * 8);
      }
      #pragma unroll
      for (int i = 0; i < 4; ++i) {
        int row = wn * 64 + i * 16 + fr;
        bfr[i] = *(const bf16x8*)(Bs + row * 64 + (gl ^ (fr & 7)) * 8);
      }
      #pragma unroll
      for (int mi = 0; mi < 4; ++mi)
        #pragma unroll
        for (int ni = 0; ni < 4; ++ni)
          acc[mi][ni] = __builtin_amdgcn_mfma_f32_16x16x32_bf16(
              af[mi], bfr[ni], acc[mi][ni], 0, 0, 0);
    }
  }

  // V-block epilogue (MODE 1, n0 >= 2048): LDS transpose, b128 V^T stores.
  if constexpr (MODE == 1) {
    if (n0 >= 2048) {
      const int b = m0 >> 11;
      const int vt0 = m0 & 2047;                     // time index base
      const int hbase = ((n0 - 2048) >> 6) & 15;     // head of col group 0
      _Float16 (*Vt)[136] = (_Float16(*)[136])smem;  // [d=64][t=128+8] 17.4KB
      #pragma unroll
      for (int half = 0; half < 2; ++half) {
        __syncthreads();     // As/Bs reads done / previous half stored
        if (wn == half) {
          #pragma unroll
          for (int mi = 0; mi < 4; ++mi) {
            int trow = wm * 64 + mi * 16 + g4;
            #pragma unroll
            for (int ni = 0; ni < 4; ++ni) {
              h4 pv;
              #pragma unroll
              for (int r = 0; r < 4; ++r) pv[r] = (_Float16)acc[mi][ni][r];
              *(h4*)(&Vt[ni * 16 + fr][trow]) = pv;
            }
          }
        }
        __syncthreads();
        size_t bh = (size_t)(b * NH + ((hbase + half) & 15));
        #pragma unroll
        for (int i = 0; i < 4; ++i) {
          int p = i * 256 + tid;               // 1024 granules (64 d x 16)
          int d = p >> 4, tg = (p & 15) * 8;
          *(uint4*)(vtb + (bh * HD + d) * T_ + vt0 + tg) = *(uint4*)(&Vt[d][tg]);
        }
      }
      return;
    }
  }

  // Scalar epilogue. C/D layout: col = lane&15, row = (lane>>4)*4 + reg.
  #pragma unroll
  for (int mi = 0; mi < 4; ++mi) {
    #pragma unroll
    for (int ni = 0; ni < 4; ++ni) {
      #pragma unroll
      for (int r = 0; r < 4; ++r) {
        int gm = m0 + wm * 64 + mi * 16 + g4 + r;
        int gn = n0 + wn * 64 + ni * 16 + fr;
        float v = acc[mi][ni][r];
        if constexpr (MODE == 0) {
          Cf[(size_t)gm * N + gn] = v;
        } else {
          int b = gm >> 11, t = gm & 2047;            // T=2048
          int s = gn >> 10, h = (gn >> 6) & 15, d = gn & 63;
          size_t bh = (size_t)(b * NH + h);
          if (s == 0) qb[(bh * T_ + t) * HD + d] = __float2bfloat16(v * EXP_SC);
          else        kb[(bh * T_ + t) * HD + d] = __float2bfloat16(v);
        }
      }
    }
  }
}

// ---------------- 128x64 BT-GEMM for the projection ----------------
__global__ __launch_bounds__(256) void gemm_bt_n64(
    const bf16* __restrict__ A, const bf16* __restrict__ BT,
    float* __restrict__ Cf, int M, int N, int K) {
  __shared__ bf16 As[128 * 64];   // 16KB
  __shared__ bf16 Bs[64 * 64];    //  8KB
  const int tid = threadIdx.x;
  const int l = tid & 63, w = tid >> 6;
  const int wm = w >> 1, wn = w & 1;          // 64m x 32n per wave
  const int m0 = blockIdx.y * 128, n0 = blockIdx.x * 64;
  const int fr = l & 15;
  const int lg = l >> 4;

  v4f acc[4][2] = {};

  for (int kt = 0; kt < K; kt += 64) {
    __syncthreads();
    #pragma unroll
    for (int i = 0; i < 4; ++i) {
      int p = i * 256 + tid;
      int row = p >> 3, g = (p & 7) ^ (row & 7);
      gld_lds16(A + (size_t)(m0 + row) * K + kt + g * 8, As + p * 8);
    }
    #pragma unroll
    for (int i = 0; i < 2; ++i) {
      int p = i * 256 + tid;
      int row = p >> 3, g = (p & 7) ^ (row & 7);
      gld_lds16(BT + (size_t)(n0 + row) * K + kt + g * 8, Bs + p * 8);
    }
    __syncthreads();
    #pragma unroll
    for (int kk = 0; kk < 64; kk += 32) {
      const int gl = (kk >> 3) + lg;
      bf16x8 af[4], bfr[2];
      #pragma unroll
      for (int i = 0; i < 4; ++i) {
        int row = wm * 64 + i * 16 + fr;
        af[i] = *(const bf16x8*)(As + row * 64 + (gl ^ (fr & 7)) * 8);
      }
      #pragma unroll
      for (int i = 0; i < 2; ++i) {
        int row = wn * 32 + i * 16 + fr;
        bfr[i] = *(const bf16x8*)(Bs + row * 64 + (gl ^ (fr & 7)) * 8);
      }
      #pragma unroll
      for (int mi = 0; mi < 4; ++mi)
        #pragma unroll
        for (int ni = 0; ni < 2; ++ni)
          acc[mi][ni] = __builtin_amdgcn_mfma_f32_16x16x32_bf16(
              af[mi], bfr[ni], acc[mi][ni], 0, 0, 0);
    }
  }

  #pragma unroll
  for (int mi = 0; mi < 4; ++mi)
    #pragma unroll
    for (int ni = 0; ni < 2; ++ni)
      #pragma unroll
      for (int r = 0; r < 4; ++r) {
        int gm = m0 + wm * 64 + mi * 16 + (l >> 4) * 4 + r;
        int gn = n0 + wn * 32 + ni * 16 + (l & 15);
        Cf[(size_t)gm * N + gn] = acc[mi][ni][r];
      }
}

// ---------------- fused attention: round-12 proven structure ----------------
// q128/Kt128, block 256 = 4 waves, wave (qh=w&1, kh=w>>1): 64 q x 64 keys per
// 128-key tile. No max subtraction (muP 1/64: exp2 can't overflow; softmax
// shift-invariant) -> partial O/l additive across key halves, one LDS combine
// at the end, direct bf16 store (no atomics -- block key-split was falsified
// round 15: cross-XCD atomic combine cost >> occupancy gain). S^T = K Q^T
// C-layout feeds packed ds_write_b64 of P; PV reads b128 A-frags at full
// K=32 f16 rate; ones-B row sums; exp2 mul-free (Q pre-scaled).
__global__ __launch_bounds__(256) void flash_attn(
    const bf16* __restrict__ Qg, const bf16* __restrict__ Kg,
    const _Float16* __restrict__ VTg, bf16* __restrict__ Og) {
  __shared__ char smem[53248];
  bf16*     Ks = (bf16*)smem;                         // [128][64] swizzled, 16KB
  _Float16* Vs = (_Float16*)(smem + 16384);           // [64][128] swizzled, 16KB
  _Float16 (*Ps)[40] = (_Float16(*)[40])(smem + 32768); // [4*64][40], 20KB
  float*    Obuf = (float*)smem;                      // combine alias: [2][64][68]
  float*    Lbuf = (float*)(smem + 34816);            // combine alias: [2][64]

  const int tid = threadIdx.x, l = tid & 63, w = tid >> 6;
  const int qh = w & 1, kh = w >> 1;
  const int fr = l & 15, fk = (l >> 4) * 8, g4 = (l >> 4) * 4, lg = l >> 4;
  const int bh = blockIdx.y, qt = blockIdx.x;
  const int q0 = qt * 128 + qh * 64;           // wave's first q-row
  const size_t base  = (size_t)bh * T_ * HD;   // Q/K base
  const size_t baseV = (size_t)bh * HD * T_;   // V^T base
  _Float16 (*Pw)[40] = Ps + w * 64;            // wave-private P rows

  // Q fragments (B-operand of S^T: n=q, k=d) in registers, loaded once.
  bf16x8 qB[4][2];
  #pragma unroll
  for (int qf = 0; qf < 4; ++qf)
    #pragma unroll
    for (int kki = 0; kki < 2; ++kki)
      qB[qf][kki] = *(const bf16x8*)(
          Qg + base + (size_t)(q0 + qf * 16 + fr) * HD + kki * 32 + fk);

  h8 ones;
  #pragma unroll
  for (int j = 0; j < 8; ++j) ones[j] = (_Float16)1.0f;

  v4f o[4][4] = {};     // partial O: m=q (4 frags), n=d (4 frags)
  v4f lacc[4] = {};     // partial row sums

  for (int kt = 0; kt < T_; kt += 128) {
    __syncthreads();
    #pragma unroll
    for (int i = 0; i < 4; ++i) {
      int p = i * 256 + tid;                   // 1024 granules each
      int krow = p >> 3, kg = (p & 7) ^ (krow & 7);
      gld_lds16(Kg + base + (size_t)(kt + krow) * HD + kg * 8, Ks + p * 8);
      int vrow = p >> 4, vg = (p & 15) ^ (vrow & 15);
      gld_lds16(VTg + baseV + (size_t)vrow * T_ + kt + vg * 8, Vs + p * 8);
    }
    __syncthreads();

    // Wave's 64 keys (half kh) in 2 chunks of 32: S^T -> exp2 -> store -> PV.
    #pragma unroll
    for (int c = 0; c < 2; ++c) {
      const int kkg = kh * 2 + c;              // global 32-key chunk 0..3
      #pragma unroll
      for (int hf = 0; hf < 2; ++hf) {
        const int kf = kkg * 2 + hf;           // global 16-key frag 0..7
        v4f st[4] = {};
        #pragma unroll
        for (int kki = 0; kki < 2; ++kki) {
          int row = kf * 16 + fr;
          bf16x8 ak = *(const bf16x8*)(
              Ks + row * 64 + ((kki * 4 + lg) ^ (fr & 7)) * 8);
          #pragma unroll
          for (int qf = 0; qf < 4; ++qf)
            st[qf] = __builtin_amdgcn_mfma_f32_16x16x32_bf16(
                ak, qB[qf][kki], st[qf], 0, 0, 0);
        }
        #pragma unroll
        for (int qf = 0; qf < 4; ++qf) {
          union { fp16x2 p2[2]; h4 p4; } u;
          u.p2[0] = __builtin_amdgcn_cvt_pkrtz(
              __builtin_amdgcn_exp2f(st[qf][0]),
              __builtin_amdgcn_exp2f(st[qf][1]));
          u.p2[1] = __builtin_amdgcn_cvt_pkrtz(
              __builtin_amdgcn_exp2f(st[qf][2]),
              __builtin_amdgcn_exp2f(st[qf][3]));
          *(h4*)(&Pw[qf * 16 + fr][hf * 16 + g4]) = u.p4;
        }
      }
      h8 ap[4], bv[4];
      #pragma unroll
      for (int qf = 0; qf < 4; ++qf)
        ap[qf] = *(const h8*)(&Pw[qf * 16 + fr][fk]);
      #pragma unroll
      for (int nf = 0; nf < 4; ++nf) {
        int row = nf * 16 + fr;
        bv[nf] = *(const h8*)(Vs + row * 128 + ((kkg * 4 + lg) ^ fr) * 8);
      }
      #pragma unroll
      for (int qf = 0; qf < 4; ++qf) {
        lacc[qf] = __builtin_amdgcn_mfma_f32_16x16x32_f16(
            ap[qf], ones, lacc[qf], 0, 0, 0);
        #pragma unroll
        for (int nf = 0; nf < 4; ++nf)
          o[qf][nf] = __builtin_amdgcn_mfma_f32_16x16x32_f16(
              ap[qf], bv[nf], o[qf][nf], 0, 0, 0);
      }
    }
  }

  // Combine key halves: waves 2,3 dump partials to LDS; waves 0,1 add + store.
  __syncthreads();           // all tiles done; Ks/Vs/Ps now dead
  if (w >= 2) {
    #pragma unroll
    for (int qf = 0; qf < 4; ++qf)
      #pragma unroll
      for (int r = 0; r < 4; ++r) {
        int row = qf * 16 + g4 + r;
        #pragma unroll
        for (int nf = 0; nf < 4; ++nf)
          Obuf[(qh * 64 + row) * 68 + nf * 16 + fr] = o[qf][nf][r];
        if (fr == 0) Lbuf[qh * 64 + row] = lacc[qf][r];
      }
  }
  __syncthreads();
  if (w < 2) {
    int b = bh >> 4, h = bh & 15;
    #pragma unroll
    for (int qf = 0; qf < 4; ++qf) {
      #pragma unroll
      for (int r = 0; r < 4; ++r) {
        int row = qf * 16 + g4 + r;
        float inv = 1.f / (lacc[qf][r] + Lbuf[qh * 64 + row]);
        int t = q0 + row;
        #pragma unroll
        for (int nf = 0; nf < 4; ++nf) {
          float val = o[qf][nf][r] + Obuf[(qh * 64 + row) * 68 + nf * 16 + fr];
          Og[((size_t)(b * T_ + t)) * DM + h * HD + nf * 16 + fr] =
              __float2bfloat16(val * inv);
        }
      }
    }
  }
}

extern "C" void kernel_launch(void* const* d_in, const int* in_sizes, int n_in,
                              void* d_out, int out_size, void* d_ws, size_t ws_size,
                              hipStream_t stream) {
  const float* x     = (const float*)d_in[0];
  const float* Wqkv  = (const float*)d_in[1];
  const float* Wproj = (const float*)d_in[2];
  float* out = (float*)d_out;
  char* ws = (char*)d_ws;

  // Workspace layout (48 MB), no overlays:
  bf16*     Xb     = (bf16*)(ws);                           //  0-8
  bf16*     WqkvT  = (bf16*)(ws + (size_t)( 8u << 20));     //  8-14
  bf16*     WprojT = (bf16*)(ws + (size_t)(14u << 20));     // 14-16
  bf16*     Qb     = (bf16*)(ws + (size_t)(16u << 20));     // 16-24 (pre-scaled)
  bf16*     Kb     = (bf16*)(ws + (size_t)(24u << 20));     // 24-32
  _Float16* VTh    = (_Float16*)(ws + (size_t)(32u << 20)); // 32-40 (by gemm1)
  bf16*     Ab     = (bf16*)(ws + (size_t)(40u << 20));     // 40-48

  prep<<<8192, 256, 0, stream>>>(x, Wqkv, Wproj, Xb, WqkvT, WprojT);

  gemm_bt<1><<<dim3(N_QKV / 128, M_ / 128), 256, 0, stream>>>(
      Xb, WqkvT, nullptr, Qb, Kb, VTh, M_, N_QKV, DM);

  flash_attn<<<dim3(T_ / 128, B_ * NH), 256, 0, stream>>>(Qb, Kb, VTh, Ab);

  gemm_bt_n64<<<dim3(DM / 64, M_ / 128), 256, 0, stream>>>(
      Ab, WprojT, out, M_, DM, DM);
}